// Round 13
// baseline (279.316 us; speedup 1.0000x reference)
//
#include <hip/hip_runtime.h>
#include <hip/hip_bf16.h>
#include <stdint.h>

#define K_D 512
#define N_C 100000
#define SCALE 64.0f

// margin constants (double-precision derived)
#define COS_M 0.87758256189037271612f
#define SIN_M 0.47942553860420300027f
#define TH   (-0.87758256189037271612f)
#define MM_C  0.23971276930210150013f

typedef __attribute__((ext_vector_type(8))) short bf16x8;
typedef __attribute__((ext_vector_type(4))) float f32x4;

#define NNB 782          // n-strips of 128 classes (782*128 = 100,096)
#define NMB 8            // m-blocks of 32 rows
#define GZ_GRID 6256     // 782*8 = 8 XCDs x 782 exactly (bijective swizzle)
#define ZSTRIDE 784

// ws byte offsets (end 1,073,152 — within proven ws capacity)
#define OFF_INVNE 0          // 256 f
#define OFF_EMB   1024       // 256*512 ushorts = 262144 (fragment-ordered)
#define OFF_TP    263168     // 768*2 f
#define OFF_ZROW  269312     // 256 f
#define OFF_ZPART 270336     // 256*784 f = 802,816

__device__ __forceinline__ uint32_t f2bf(float f) {
    __hip_bfloat16 h = __float2bfloat16(f);
    return (uint32_t)__builtin_bit_cast(ushort, h);
}

// ---------------- threefry2x32 (JAX, key=42) ----------------
__device__ __forceinline__ void threefry(uint32_t x0, uint32_t x1, uint32_t& o0, uint32_t& o1) {
    const uint32_t k0 = 0u, k1 = 42u;
    const uint32_t k2 = k0 ^ k1 ^ 0x1BD11BDAu;
    const uint32_t ks[3] = {k0, k1, k2};
    x0 += k0; x1 += k1;
    const int rot0[4] = {13, 15, 26, 6};
    const int rot1[4] = {17, 29, 16, 24};
    #pragma unroll
    for (int grp = 0; grp < 5; ++grp) {
        const int* r = (grp & 1) ? rot1 : rot0;
        #pragma unroll
        for (int i = 0; i < 4; ++i) {
            x0 += x1;
            x1 = (x1 << r[i]) | (x1 >> (32 - r[i]));
            x1 ^= x0;
        }
        x0 += ks[(grp + 1) % 3];
        x1 += ks[(grp + 2) % 3] + (uint32_t)(grp + 1);
    }
    o0 = x0; o1 = x1;
}

// ---------------- fused prep (blocks 0-63) + targets (blocks 64-255) ----------
__global__ __launch_bounds__(256) void prep_target(const float* __restrict__ E,
                                                   const float* __restrict__ W,
                                                   const int* __restrict__ ll,
                                                   ushort* __restrict__ Ebf,
                                                   float* __restrict__ invne,
                                                   float* __restrict__ tp) {
    const int w = threadIdx.x >> 6, lane = threadIdx.x & 63;
    if (blockIdx.x < 64) {
        const int row = blockIdx.x * 4 + w;
        const float4* src = (const float4*)(E + (size_t)row * K_D);
        float4 a = src[2 * lane];
        float4 b = src[2 * lane + 1];
        float ss = a.x*a.x + a.y*a.y + a.z*a.z + a.w*a.w
                 + b.x*b.x + b.y*b.y + b.z*b.z + b.w*b.w;
        #pragma unroll
        for (int m = 32; m >= 1; m >>= 1) ss += __shfl_xor(ss, m, 64);
        uint4 pk;
        pk.x = f2bf(a.x) | (f2bf(a.y) << 16);
        pk.y = f2bf(a.z) | (f2bf(a.w) << 16);
        pk.z = f2bf(b.x) | (f2bf(b.y) << 16);
        pk.w = f2bf(b.z) | (f2bf(b.w) << 16);
        const int kstep = lane >> 2, gg = lane & 3;
        const size_t slot = ((size_t)(row >> 4) * 16 + kstep) * 64 + (row & 15) + (gg << 4);
        ((uint4*)Ebf)[slot] = pk;
        if (lane == 0) invne[row] = rsqrtf(ss + 1e-12f);
        return;
    }

    const int p = (blockIdx.x - 64) * 4 + w;   // 768 pairs
    const int b = p / 3;
    const int jj = p - b * 3;
    float u[8];
    #pragma unroll
    for (int j = 0; j < 8; ++j) {
        int n = b * 8 + j;
        uint32_t x0, x1, o0, o1;
        if (n < 1024) { x0 = (uint32_t)n; x1 = (uint32_t)(n + 1024); }
        else          { x0 = (uint32_t)(n - 1024); x1 = (uint32_t)n; }
        threefry(x0, x1, o0, o1);
        uint32_t bits = (n < 1024) ? o0 : o1;
        uint32_t fb = (bits >> 9) | 0x3F800000u;
        u[j] = __builtin_bit_cast(float, fb) - 1.0f;
    }
    bool used[8] = {false,false,false,false,false,false,false,false};
    int sel = 0;
    for (int s = 0; s <= jj; ++s) {
        float bv = 2.0f; int bi = 0;
        for (int i = 0; i < 8; ++i)
            if (!used[i] && u[i] < bv) { bv = u[i]; bi = i; }
        used[bi] = true;
        sel = bi;
    }
    const int c = ll[b * 8 + sel];

    const float4* ep = (const float4*)(E + (size_t)b * K_D);
    const float4* wp = (const float4*)(W + (size_t)c * K_D);
    float4 e0 = ep[lane], e1 = ep[lane + 64];
    float4 w0 = wp[lane], w1 = wp[lane + 64];
    float dot = e0.x*w0.x + e0.y*w0.y + e0.z*w0.z + e0.w*w0.w
              + e1.x*w1.x + e1.y*w1.y + e1.z*w1.z + e1.w*w1.w;
    float esq = e0.x*e0.x + e0.y*e0.y + e0.z*e0.z + e0.w*e0.w
              + e1.x*e1.x + e1.y*e1.y + e1.z*e1.z + e1.w*e1.w;
    float wsq = w0.x*w0.x + w0.y*w0.y + w0.z*w0.z + w0.w*w0.w
              + w1.x*w1.x + w1.y*w1.y + w1.z*w1.z + w1.w*w1.w;
    #pragma unroll
    for (int m = 32; m >= 1; m >>= 1) {
        dot += __shfl_xor(dot, m, 64);
        esq += __shfl_xor(esq, m, 64);
        wsq += __shfl_xor(wsq, m, 64);
    }
    if (lane == 0) {
        float t = dot * rsqrtf(esq + 1e-12f) * rsqrtf(wsq + 1e-12f);
        t = fminf(1.0f, fmaxf(-1.0f, t));
        float tc = fminf(1.0f - 1e-7f, fmaxf(-1.0f + 1e-7f, t));
        float marg = tc * COS_M - sqrtf(fmaxf(0.0f, 1.0f - tc * tc)) * SIN_M;
        float ft = (t > TH) ? marg : (t - MM_C);
        tp[p * 2]     = t;
        tp[p * 2 + 1] = ft;
    }
}

// ---------------- fused GEMM + exp-sum: ZERO-global inner loop ----------------
// 512 thr / 8 waves. Block: M=32 (rows mb*32) x N=128 (strip nb). Grid 6256,
// bijective XCD swizzle: a strip's 8 m-blocks run adjacent on one XCD -> its
// 256 KB W panel is L2-resident (one HBM fetch per strip).
// LDS = 64 KB exactly: A tile 32 KB (copied once from Ebf, contiguous) +
// W K-slice double-buffer 2 x 16 KB (128 classes x 64 k, bf16 frag-order).
// 8 K-phases: ISSUE (coalesced fp32 W->regs) | PROCESS (ssq + cvt + ds_write)
// | COMPUTE (ds_read_b128 + 4 MFMA/wave, no global) | lgkm-only barrier.
// Single epilogue (K-chunked => one exp pass at the end).
__global__ __launch_bounds__(512, 4) void gemm_z(const float* __restrict__ W,
                                                 const ushort* __restrict__ Ebf,
                                                 const float* __restrict__ invne,
                                                 float* __restrict__ zpart) {
    __shared__ ushort pool[32768];   // [0,16384): A  [16384,32768): W dbuf

    const int tid  = threadIdx.x;
    const int lane = tid & 63, wv = tid >> 6;     // wv 0..7
    const int r16  = lane & 15, g = lane >> 4;

    const int wid = (blockIdx.x & 7) * 782 + (blockIdx.x >> 3);
    const int nb  = wid >> 3;          // 0..781
    const int mb  = wid & 7;           // 0..7
    const int cb  = nb * 128;
    const int r0  = mb * 32;

    // W staging identity: thread owns class c_loc = tid>>2, quarter q = tid&3
    // (16 k-floats per phase: k = phase*64 + q*16 .. +16)
    const int c_loc = tid >> 2;
    const int q     = tid & 3;
    const int cls_g = cb + c_loc;
    const float* wsrc = W + (size_t)(cls_g < N_C ? cls_g : N_C - 1) * K_D + q * 16;

    float4 pf[4];
    float ssq = 0.f;

    #define ISSUE(P) {                                                          \
        const float4* s4 = (const float4*)(wsrc + (P) * 64);                    \
        pf[0] = s4[0]; pf[1] = s4[1]; pf[2] = s4[2]; pf[3] = s4[3]; }

    ISSUE(0);

    // A: one contiguous 32 KB copy from Ebf (frag-ordered tiles 2mb, 2mb+1)
    {
        const uint4* asrc = (const uint4*)(Ebf + (size_t)mb * 16384);
        uint4* adst = (uint4*)pool;
        #pragma unroll
        for (int j = 0; j < 4; ++j) adst[tid * 4 + j] = asrc[tid * 4 + j];
    }

    // per-row inverse embedding norms (hoisted; L2-hot, tiny)
    float inew[2][4];
    #pragma unroll
    for (int mt = 0; mt < 2; ++mt)
        #pragma unroll
        for (int i = 0; i < 4; ++i)
            inew[mt][i] = invne[r0 + mt * 16 + g * 4 + i];

    // ssq-accum + cvt + 2 frag-order b128 writes into buf (P)&1
    #define PROCESS(P) {                                                        \
        ushort* wt = pool + 16384 + ((P) & 1) * 8192;                           \
        ssq += pf[0].x*pf[0].x + pf[0].y*pf[0].y + pf[0].z*pf[0].z + pf[0].w*pf[0].w \
             + pf[1].x*pf[1].x + pf[1].y*pf[1].y + pf[1].z*pf[1].z + pf[1].w*pf[1].w \
             + pf[2].x*pf[2].x + pf[2].y*pf[2].y + pf[2].z*pf[2].z + pf[2].w*pf[2].w \
             + pf[3].x*pf[3].x + pf[3].y*pf[3].y + pf[3].z*pf[3].z + pf[3].w*pf[3].w; \
        const int nt = c_loc >> 4, cl = c_loc & 15, ksl = q >> 1;               \
        _Pragma("unroll")                                                       \
        for (int h = 0; h < 2; ++h) {                                           \
            const int gg = (q & 1) * 2 + h;                                     \
            uint4 pk;                                                           \
            pk.x = f2bf(pf[2*h].x)   | (f2bf(pf[2*h].y)   << 16);               \
            pk.y = f2bf(pf[2*h].z)   | (f2bf(pf[2*h].w)   << 16);               \
            pk.z = f2bf(pf[2*h+1].x) | (f2bf(pf[2*h+1].y) << 16);               \
            pk.w = f2bf(pf[2*h+1].z) | (f2bf(pf[2*h+1].w) << 16);               \
            *(uint4*)&wt[(nt * 2 + ksl) * 512 + (cl + gg * 16) * 8] = pk;       \
        }                                                                       \
    }

    f32x4 acc0 = {}, acc1 = {};

    // pure LDS + MFMA: 2 ks-steps x (2 A-reads + 1 B-read + 2 MFMA)
    #define COMPUTE(P) {                                                        \
        const ushort* wt = pool + 16384 + ((P) & 1) * 8192;                     \
        _Pragma("unroll")                                                       \
        for (int ksl = 0; ksl < 2; ++ksl) {                                     \
            const int ksg = (P) * 2 + ksl;                                      \
            bf16x8 a0 = *(const bf16x8*)&pool[(ksg * 64 + lane) * 8];           \
            bf16x8 a1 = *(const bf16x8*)&pool[((16 + ksg) * 64 + lane) * 8];    \
            bf16x8 bv = *(const bf16x8*)&wt[(wv * 2 + ksl) * 512 + lane * 8];   \
            acc0 = __builtin_amdgcn_mfma_f32_16x16x32_bf16(a0, bv, acc0, 0, 0, 0); \
            acc1 = __builtin_amdgcn_mfma_f32_16x16x32_bf16(a1, bv, acc1, 0, 0, 0); \
        }                                                                       \
    }

    #define PHASE_END() { asm volatile("s_waitcnt lgkmcnt(0)" ::: "memory");    \
                          __builtin_amdgcn_s_barrier();                         \
                          __builtin_amdgcn_sched_barrier(0); }

    // prologue
    PROCESS(0);
    ISSUE(1);
    PHASE_END();
    // 8 K-phases; vmcnt never drained at a barrier
    for (int p = 0; p < 8; ++p) {
        COMPUTE(p);
        if (p < 7) PROCESS(p + 1);
        if (p < 6) ISSUE(p + 2);
        PHASE_END();
    }

    #undef ISSUE
    #undef PROCESS
    #undef COMPUTE
    #undef PHASE_END

    // ---- epilogue (A region of pool is dead; overlay sp + zred on it) ----
    // finalize per-class ssq: quarters live in lane bits 0-1
    ssq += __shfl_xor(ssq, 1, 64);
    ssq += __shfl_xor(ssq, 2, 64);
    float* spf   = (float*)pool;          // 128 f
    float* zredf = (float*)pool + 128;    // 32 rows x 8 waves
    if ((lane & 3) == 0) spf[c_loc] = ssq;
    __syncthreads();

    const float iw  = rsqrtf(spf[wv * 16 + r16] + 1e-12f);
    const bool  vld = (cb + wv * 16 + r16) < N_C;

    #pragma unroll
    for (int mt = 0; mt < 2; ++mt) {
        #pragma unroll
        for (int i = 0; i < 4; ++i) {
            float cv = (mt ? acc1[i] : acc0[i]) * iw * inew[mt][i];
            cv = fminf(1.0f, fmaxf(-1.0f, cv));
            float e = vld ? __expf(SCALE * cv - 64.0f) : 0.f;
            e += __shfl_xor(e, 1, 64);
            e += __shfl_xor(e, 2, 64);
            e += __shfl_xor(e, 4, 64);
            e += __shfl_xor(e, 8, 64);
            if (r16 == 0) zredf[(mt * 16 + g * 4 + i) * 8 + wv] = e;
        }
    }
    __syncthreads();
    if (tid < 32) {
        float s = 0.f;
        #pragma unroll
        for (int v = 0; v < 8; ++v) s += zredf[tid * 8 + v];
        zpart[(size_t)(r0 + tid) * ZSTRIDE + nb] = s;
    }
}

// ---------------- per-row Z reduction (coalesced) ----------------
__global__ __launch_bounds__(256) void zrow_kernel(const float* __restrict__ zpart,
                                                   float* __restrict__ zrow) {
    const int b = blockIdx.x;
    float sum = 0.f;
    for (int t = threadIdx.x; t < NNB; t += 256)
        sum += zpart[(size_t)b * ZSTRIDE + t];
    __shared__ float red[256];
    red[threadIdx.x] = sum;
    __syncthreads();
    for (int st = 128; st >= 1; st >>= 1) {
        if (threadIdx.x < st) red[threadIdx.x] += red[threadIdx.x + st];
        __syncthreads();
    }
    if (threadIdx.x == 0) zrow[b] = red[0];
}

// ---------------- final loss ----------------
__global__ __launch_bounds__(256) void loss_kernel(const float* __restrict__ zrow,
                                                   const float* __restrict__ tp,
                                                   float* __restrict__ out) {
    const int b = threadIdx.x;
    const float Z = zrow[b];
    float lsum = 0.f;
    #pragma unroll
    for (int j = 0; j < 3; ++j) {
        float t  = tp[(b * 3 + j) * 2];
        float ft = tp[(b * 3 + j) * 2 + 1];
        float S = Z - expf(SCALE * t - 64.0f) + expf(SCALE * ft - 64.0f);
        lsum += logf(S) + 64.0f - SCALE * ft;
    }
    __shared__ float red[256];
    red[b] = lsum;
    __syncthreads();
    for (int st = 128; st >= 1; st >>= 1) {
        if (b < st) red[b] += red[b + st];
        __syncthreads();
    }
    if (b == 0) out[0] = red[0] / 768.0f;
}

extern "C" void kernel_launch(void* const* d_in, const int* in_sizes, int n_in,
                              void* d_out, int out_size, void* d_ws, size_t ws_size,
                              hipStream_t stream) {
    const float* E = (const float*)d_in[0];
    const float* W = (const float*)d_in[1];
    const int*  LL = (const int*)d_in[2];
    char* ws = (char*)d_ws;
    float*  invne = (float*)(ws + OFF_INVNE);
    ushort* Ebf   = (ushort*)(ws + OFF_EMB);
    float*  tp    = (float*)(ws + OFF_TP);
    float*  zrow  = (float*)(ws + OFF_ZROW);
    float*  zpart = (float*)(ws + OFF_ZPART);
    float*  out   = (float*)d_out;

    hipLaunchKernelGGL(prep_target, dim3(256),     dim3(256), 0, stream,
                       E, W, LL, Ebf, invne, tp);
    hipLaunchKernelGGL(gemm_z,      dim3(GZ_GRID), dim3(512), 0, stream,
                       W, Ebf, invne, zpart);
    hipLaunchKernelGGL(zrow_kernel, dim3(256),     dim3(256), 0, stream,
                       zpart, zrow);
    hipLaunchKernelGGL(loss_kernel, dim3(1),       dim3(256), 0, stream,
                       zrow, tp, out);
}

// Round 14
// 91.819 us; speedup vs baseline: 3.0420x; 3.0420x over previous
//
#include <hip/hip_runtime.h>
#include <hip/hip_bf16.h>
#include <stdint.h>

#define K_D 512
#define N_C 100000
#define SCALE 64.0f

// margin constants (double-precision derived)
#define COS_M 0.87758256189037271612f
#define SIN_M 0.47942553860420300027f
#define TH   (-0.87758256189037271612f)
#define MM_C  0.23971276930210150013f

typedef __attribute__((ext_vector_type(8))) short bf16x8;
typedef __attribute__((ext_vector_type(4))) float f32x4;

#define NNB 782          // n-blocks of 128 classes (782*128 = 100,096)
#define ZSTRIDE 784

// ws byte offsets (end 1,073,152 — within proven ws capacity)
#define OFF_INVNE 0          // 256 f
#define OFF_EMB   1024       // 256*512 ushorts = 262144 (fragment-ordered)
#define OFF_TP    263168     // 768*2 f
#define OFF_ZROW  269312     // 256 f
#define OFF_ZPART 270336     // 256*784 f = 802,816

__device__ __forceinline__ uint32_t f2bf(float f) {
    __hip_bfloat16 h = __float2bfloat16(f);
    return (uint32_t)__builtin_bit_cast(ushort, h);
}

// ---------------- threefry2x32 (JAX, key=42) ----------------
__device__ __forceinline__ void threefry(uint32_t x0, uint32_t x1, uint32_t& o0, uint32_t& o1) {
    const uint32_t k0 = 0u, k1 = 42u;
    const uint32_t k2 = k0 ^ k1 ^ 0x1BD11BDAu;
    const uint32_t ks[3] = {k0, k1, k2};
    x0 += k0; x1 += k1;
    const int rot0[4] = {13, 15, 26, 6};
    const int rot1[4] = {17, 29, 16, 24};
    #pragma unroll
    for (int grp = 0; grp < 5; ++grp) {
        const int* r = (grp & 1) ? rot1 : rot0;
        #pragma unroll
        for (int i = 0; i < 4; ++i) {
            x0 += x1;
            x1 = (x1 << r[i]) | (x1 >> (32 - r[i]));
            x1 ^= x0;
        }
        x0 += ks[(grp + 1) % 3];
        x1 += ks[(grp + 2) % 3] + (uint32_t)(grp + 1);
    }
    o0 = x0; o1 = x1;
}

// ---------------- fused prep (blocks 0-63) + targets (blocks 64-255) ----------
// prep: fragment-ordered bf16 copy of E + inv row norms.
// Ebf slot = ((row>>4)*16 + ks)*64 + (row&15) + g*16 (8 ushorts per slot).
// targets: inline threefry label shuffle + precise fp32 cosine + margin.
__global__ __launch_bounds__(256) void prep_target(const float* __restrict__ E,
                                                   const float* __restrict__ W,
                                                   const int* __restrict__ ll,
                                                   ushort* __restrict__ Ebf,
                                                   float* __restrict__ invne,
                                                   float* __restrict__ tp) {
    const int w = threadIdx.x >> 6, lane = threadIdx.x & 63;
    if (blockIdx.x < 64) {
        const int row = blockIdx.x * 4 + w;
        const float4* src = (const float4*)(E + (size_t)row * K_D);
        float4 a = src[2 * lane];
        float4 b = src[2 * lane + 1];
        float ss = a.x*a.x + a.y*a.y + a.z*a.z + a.w*a.w
                 + b.x*b.x + b.y*b.y + b.z*b.z + b.w*b.w;
        #pragma unroll
        for (int m = 32; m >= 1; m >>= 1) ss += __shfl_xor(ss, m, 64);
        uint4 pk;
        pk.x = f2bf(a.x) | (f2bf(a.y) << 16);
        pk.y = f2bf(a.z) | (f2bf(a.w) << 16);
        pk.z = f2bf(b.x) | (f2bf(b.y) << 16);
        pk.w = f2bf(b.z) | (f2bf(b.w) << 16);
        const int kstep = lane >> 2, gg = lane & 3;
        const size_t slot = ((size_t)(row >> 4) * 16 + kstep) * 64 + (row & 15) + (gg << 4);
        ((uint4*)Ebf)[slot] = pk;
        if (lane == 0) invne[row] = rsqrtf(ss + 1e-12f);
        return;
    }

    const int p = (blockIdx.x - 64) * 4 + w;   // 768 pairs
    const int b = p / 3;
    const int jj = p - b * 3;
    float u[8];
    #pragma unroll
    for (int j = 0; j < 8; ++j) {
        int n = b * 8 + j;
        uint32_t x0, x1, o0, o1;
        if (n < 1024) { x0 = (uint32_t)n; x1 = (uint32_t)(n + 1024); }
        else          { x0 = (uint32_t)(n - 1024); x1 = (uint32_t)n; }
        threefry(x0, x1, o0, o1);
        uint32_t bits = (n < 1024) ? o0 : o1;
        uint32_t fb = (bits >> 9) | 0x3F800000u;
        u[j] = __builtin_bit_cast(float, fb) - 1.0f;
    }
    bool used[8] = {false,false,false,false,false,false,false,false};
    int sel = 0;
    for (int s = 0; s <= jj; ++s) {
        float bv = 2.0f; int bi = 0;
        for (int i = 0; i < 8; ++i)
            if (!used[i] && u[i] < bv) { bv = u[i]; bi = i; }
        used[bi] = true;
        sel = bi;
    }
    const int c = ll[b * 8 + sel];

    const float4* ep = (const float4*)(E + (size_t)b * K_D);
    const float4* wp = (const float4*)(W + (size_t)c * K_D);
    float4 e0 = ep[lane], e1 = ep[lane + 64];
    float4 w0 = wp[lane], w1 = wp[lane + 64];
    float dot = e0.x*w0.x + e0.y*w0.y + e0.z*w0.z + e0.w*w0.w
              + e1.x*w1.x + e1.y*w1.y + e1.z*w1.z + e1.w*w1.w;
    float esq = e0.x*e0.x + e0.y*e0.y + e0.z*e0.z + e0.w*e0.w
              + e1.x*e1.x + e1.y*e1.y + e1.z*e1.z + e1.w*e1.w;
    float wsq = w0.x*w0.x + w0.y*w0.y + w0.z*w0.z + w0.w*w0.w
              + w1.x*w1.x + w1.y*w1.y + w1.z*w1.z + w1.w*w1.w;
    #pragma unroll
    for (int m = 32; m >= 1; m >>= 1) {
        dot += __shfl_xor(dot, m, 64);
        esq += __shfl_xor(esq, m, 64);
        wsq += __shfl_xor(wsq, m, 64);
    }
    if (lane == 0) {
        float t = dot * rsqrtf(esq + 1e-12f) * rsqrtf(wsq + 1e-12f);
        t = fminf(1.0f, fmaxf(-1.0f, t));
        float tc = fminf(1.0f - 1e-7f, fmaxf(-1.0f + 1e-7f, t));
        float marg = tc * COS_M - sqrtf(fmaxf(0.0f, 1.0f - tc * tc)) * SIN_M;
        float ft = (t > TH) ? marg : (t - MM_C);
        tp[p * 2]     = t;
        tp[p * 2 + 1] = ft;
    }
}

// ---------------- fused GEMM + exp-sum (proven best: R9/R12 structure) --------
// 512 thr / 8 waves. Block: M=256 x N=128 (grid 782, W read ONCE from HBM).
// W chunk = 32 classes: fp32->regs (coalesced rows) -> exact ssq (wave shuffle)
// -> cvt bf16 once -> ds_write frag-order; dbuf 64 KB. K-loop: Ebf A-loads
// (L2-hot) + ds_read_b128 + MFMA. Schedule: COMPUTE(ch) | PROCESS(ch+1) |
// ISSUE(ch+2) | lgkm+barrier — vmcnt never drained at a barrier.
__global__ __launch_bounds__(512, 2) void gemm_z(const float* __restrict__ W,
                                                 const ushort* __restrict__ Ebf,
                                                 const float* __restrict__ invne,
                                                 float* __restrict__ zpart) {
    __shared__ ushort Wt[2][32 * 512];   // [buf][(nt*16+ks)*512 + (cl+g*16)*8]
    __shared__ float sp[2][32];          // per-class ssq

    const int tid  = threadIdx.x;
    const int lane = tid & 63, wv = tid >> 6;     // wv 0..7
    const int r16  = lane & 15, g = lane >> 4;
    const int nb   = blockIdx.x;
    const int cb   = nb * 128;

    float4 pf[4][2];   // staging regs: [row-of-4][half]; fully static indexing

    #define ISSUE(CH)                                                           \
        if ((CH) < 4) {                                                         \
            _Pragma("unroll")                                                   \
            for (int rr = 0; rr < 4; ++rr) {                                    \
                int cls = cb + (CH) * 32 + wv * 4 + rr;                         \
                const float4* src = (const float4*)(W +                         \
                    (size_t)(cls < N_C ? cls : N_C - 1) * K_D);                 \
                pf[rr][0] = src[lane];                                          \
                pf[rr][1] = src[lane + 64];                                     \
            }                                                                   \
        }

    ISSUE(0);

    // A into registers: rows wv*32 .. wv*32+31 (mt = 0,1), all of K. L2-hot.
    bf16x8 areg[2][16];
    #pragma unroll
    for (int mt = 0; mt < 2; ++mt)
        #pragma unroll
        for (int ks = 0; ks < 16; ++ks)
            areg[mt][ks] = *(const bf16x8*)(Ebf
                + (size_t)(wv * 2 + mt) * 8192 + ks * 512 + lane * 8);

    // per-row inverse embedding norms for this lane's acc rows
    float inew[2][4];
    #pragma unroll
    for (int mt = 0; mt < 2; ++mt)
        #pragma unroll
        for (int i = 0; i < 4; ++i)
            inew[mt][i] = invne[wv * 32 + mt * 16 + g * 4 + i];

    float zacc[2][4] = {};

    #define PROCESS(CH)                                                         \
        {                                                                       \
            const int B = (CH) & 1;                                             \
            _Pragma("unroll")                                                   \
            for (int rr = 0; rr < 4; ++rr) {                                    \
                const int cl32 = wv * 4 + rr;                                   \
                const int nt = cl32 >> 4, cl = cl32 & 15;                       \
                float4 a4 = pf[rr][0], b4 = pf[rr][1];                          \
                float s = a4.x*a4.x + a4.y*a4.y + a4.z*a4.z + a4.w*a4.w         \
                        + b4.x*b4.x + b4.y*b4.y + b4.z*b4.z + b4.w*b4.w;        \
                _Pragma("unroll")                                               \
                for (int m = 32; m >= 1; m >>= 1) s += __shfl_xor(s, m, 64);    \
                if (lane == 0) sp[B][cl32] = s;                                 \
                _Pragma("unroll")                                               \
                for (int h = 0; h < 2; ++h) {                                   \
                    const int k4 = h * 64 + lane;                               \
                    const int ks = k4 >> 3, gg = (k4 >> 1) & 3, hf = k4 & 1;    \
                    float4 v = pf[rr][h];                                       \
                    uint2 pk;                                                   \
                    pk.x = f2bf(v.x) | (f2bf(v.y) << 16);                       \
                    pk.y = f2bf(v.z) | (f2bf(v.w) << 16);                       \
                    *(uint2*)&Wt[B][(nt * 16 + ks) * 512 + (cl + gg * 16) * 8   \
                                    + hf * 4] = pk;                             \
                }                                                               \
            }                                                                   \
        }

    #define COMPUTE(CH)                                                         \
        {                                                                       \
            const int B = (CH) & 1;                                             \
            f32x4 acc00 = {}, acc01 = {}, acc10 = {}, acc11 = {};               \
            const ushort* bb = &Wt[B][lane * 8];                                \
            _Pragma("unroll")                                                   \
            for (int ks = 0; ks < 16; ++ks) {                                   \
                bf16x8 b0 = *(const bf16x8*)(bb + ks * 512);                    \
                bf16x8 b1 = *(const bf16x8*)(bb + 8192 + ks * 512);             \
                acc00 = __builtin_amdgcn_mfma_f32_16x16x32_bf16(                \
                            areg[0][ks], b0, acc00, 0, 0, 0);                   \
                acc01 = __builtin_amdgcn_mfma_f32_16x16x32_bf16(                \
                            areg[1][ks], b0, acc01, 0, 0, 0);                   \
                acc10 = __builtin_amdgcn_mfma_f32_16x16x32_bf16(                \
                            areg[0][ks], b1, acc10, 0, 0, 0);                   \
                acc11 = __builtin_amdgcn_mfma_f32_16x16x32_bf16(                \
                            areg[1][ks], b1, acc11, 0, 0, 0);                   \
            }                                                                   \
            _Pragma("unroll")                                                   \
            for (int nt = 0; nt < 2; ++nt) {                                    \
                const int cls = cb + (CH) * 32 + nt * 16 + r16;                 \
                const float iw = rsqrtf(sp[B][nt * 16 + r16] + 1e-12f);         \
                const bool vld = cls < N_C;                                     \
                _Pragma("unroll")                                               \
                for (int i = 0; i < 4; ++i) {                                   \
                    float c0 = (nt ? acc10[i] : acc00[i]) * iw * inew[0][i];    \
                    float c1 = (nt ? acc11[i] : acc01[i]) * iw * inew[1][i];    \
                    c0 = fminf(1.0f, fmaxf(-1.0f, c0));                         \
                    c1 = fminf(1.0f, fmaxf(-1.0f, c1));                         \
                    zacc[0][i] += vld ? __expf(SCALE * c0 - 64.0f) : 0.f;       \
                    zacc[1][i] += vld ? __expf(SCALE * c1 - 64.0f) : 0.f;       \
                }                                                               \
            }                                                                   \
        }

    #define PHASE_END() { asm volatile("s_waitcnt lgkmcnt(0)" ::: "memory");    \
                          __builtin_amdgcn_s_barrier();                         \
                          __builtin_amdgcn_sched_barrier(0); }

    PROCESS(0);
    ISSUE(1);
    PHASE_END();
    COMPUTE(0);  PROCESS(1);  ISSUE(2);  PHASE_END();
    COMPUTE(1);  PROCESS(2);  ISSUE(3);  PHASE_END();
    COMPUTE(2);  PROCESS(3);             PHASE_END();
    COMPUTE(3);

    #undef ISSUE
    #undef PROCESS
    #undef COMPUTE
    #undef PHASE_END

    // reduce zacc over the 16 classes (r16 lanes); write this wave's rows
    #pragma unroll
    for (int mt = 0; mt < 2; ++mt)
        #pragma unroll
        for (int i = 0; i < 4; ++i) {
            float v = zacc[mt][i];
            v += __shfl_xor(v, 1, 64);
            v += __shfl_xor(v, 2, 64);
            v += __shfl_xor(v, 4, 64);
            v += __shfl_xor(v, 8, 64);
            if (r16 == mt * 4 + i) {
                const int row = wv * 32 + mt * 16 + g * 4 + i;
                zpart[(size_t)row * ZSTRIDE + nb] = v;
            }
        }
}

// ---------------- per-row Z reduction (coalesced) ----------------
__global__ __launch_bounds__(256) void zrow_kernel(const float* __restrict__ zpart,
                                                   float* __restrict__ zrow) {
    const int b = blockIdx.x;
    float sum = 0.f;
    for (int t = threadIdx.x; t < NNB; t += 256)
        sum += zpart[(size_t)b * ZSTRIDE + t];
    __shared__ float red[256];
    red[threadIdx.x] = sum;
    __syncthreads();
    for (int st = 128; st >= 1; st >>= 1) {
        if (threadIdx.x < st) red[threadIdx.x] += red[threadIdx.x + st];
        __syncthreads();
    }
    if (threadIdx.x == 0) zrow[b] = red[0];
}

// ---------------- final loss ----------------
__global__ __launch_bounds__(256) void loss_kernel(const float* __restrict__ zrow,
                                                   const float* __restrict__ tp,
                                                   float* __restrict__ out) {
    const int b = threadIdx.x;
    const float Z = zrow[b];
    float lsum = 0.f;
    #pragma unroll
    for (int j = 0; j < 3; ++j) {
        float t  = tp[(b * 3 + j) * 2];
        float ft = tp[(b * 3 + j) * 2 + 1];
        float S = Z - expf(SCALE * t - 64.0f) + expf(SCALE * ft - 64.0f);
        lsum += logf(S) + 64.0f - SCALE * ft;
    }
    __shared__ float red[256];
    red[b] = lsum;
    __syncthreads();
    for (int st = 128; st >= 1; st >>= 1) {
        if (b < st) red[b] += red[b + st];
        __syncthreads();
    }
    if (b == 0) out[0] = red[0] / 768.0f;
}

extern "C" void kernel_launch(void* const* d_in, const int* in_sizes, int n_in,
                              void* d_out, int out_size, void* d_ws, size_t ws_size,
                              hipStream_t stream) {
    const float* E = (const float*)d_in[0];
    const float* W = (const float*)d_in[1];
    const int*  LL = (const int*)d_in[2];
    char* ws = (char*)d_ws;
    float*  invne = (float*)(ws + OFF_INVNE);
    ushort* Ebf   = (ushort*)(ws + OFF_EMB);
    float*  tp    = (float*)(ws + OFF_TP);
    float*  zrow  = (float*)(ws + OFF_ZROW);
    float*  zpart = (float*)(ws + OFF_ZPART);
    float*  out   = (float*)d_out;

    hipLaunchKernelGGL(prep_target, dim3(256),  dim3(256), 0, stream,
                       E, W, LL, Ebf, invne, tp);
    hipLaunchKernelGGL(gemm_z,      dim3(NNB),  dim3(512), 0, stream,
                       W, Ebf, invne, zpart);
    hipLaunchKernelGGL(zrow_kernel, dim3(256),  dim3(256), 0, stream,
                       zpart, zrow);
    hipLaunchKernelGGL(loss_kernel, dim3(1),    dim3(256), 0, stream,
                       zrow, tp, out);
}